// Round 2
// baseline (390.171 us; speedup 1.0000x reference)
//
#include <hip/hip_runtime.h>

// out[b,i,o] = S[b,i,:]·W[o,:] + A[b,i]*bias[o]
//   S[b,i,d] = sum_j adj[b,i,j]*text[b,j,d]  (L2-bound term)
//            + sum_j adj[b,i,j]*dep[b,j,i,d] (HBM stream, 268 MB — the roofline)
//   A[b,i]   = sum_j adj[b,i,j]
// B=4, L=256, D=256. dep loop: 8 independent 1KB wave-loads in flight.

#define LL 256
#define DD 256
#define D4 64   // DD/4

__global__ __launch_bounds__(256) void tgc_fused_kernel(
    const float* __restrict__ text,     // [B,L,D]
    const float* __restrict__ adj,      // [B,L,L]
    const float* __restrict__ dep,      // [B,L,L,D]
    const float* __restrict__ W,        // [Do,Di] row-major
    const float* __restrict__ bias,     // [Do]
    float* __restrict__ out)            // [B,L,Do]
{
    const int bi = blockIdx.x;          // b*L + i
    const int b  = bi >> 8;
    const int i  = bi & 255;
    const int t  = threadIdx.x;
    const int g  = t >> 6;              // j-group 0..3 (j ≡ g mod 4)
    const int l  = t & 63;              // lane: covers d = 4l..4l+3

    __shared__ float  adjs[LL];
    __shared__ float4 red[4][64];
    __shared__ float  ared[4];
    __shared__ float4 sfin[64];

    adjs[t] = adj[bi * LL + t];
    __syncthreads();

    const float4* __restrict__ dep4  = (const float4*)dep;
    const float4* __restrict__ text4 = (const float4*)text;

    float4 acc = make_float4(0.f, 0.f, 0.f, 0.f);
    float  asum = 0.f;

    // ---- dep stream: group g handles j = 32*it + 4*k + g, k=0..7 ----
    // 8 independent loads issued per iteration -> 8KB in flight per wave.
    const float4* dp = dep4 + (((size_t)(b * LL + g) * LL + i) * D4 + l);
    const size_t  JS = (size_t)4 * LL * D4;   // +4 in j

    #pragma unroll 1
    for (int it = 0; it < 8; ++it) {
        const int jb = (it << 5) + g;
        const float a0 = adjs[jb +  0];
        const float a1 = adjs[jb +  4];
        const float a2 = adjs[jb +  8];
        const float a3 = adjs[jb + 12];
        const float a4 = adjs[jb + 16];
        const float a5 = adjs[jb + 20];
        const float a6 = adjs[jb + 24];
        const float a7 = adjs[jb + 28];
        const float4 d0 = dp[0 * JS];
        const float4 d1 = dp[1 * JS];
        const float4 d2 = dp[2 * JS];
        const float4 d3 = dp[3 * JS];
        const float4 d4v = dp[4 * JS];
        const float4 d5 = dp[5 * JS];
        const float4 d6 = dp[6 * JS];
        const float4 d7 = dp[7 * JS];
        acc.x += a0*d0.x + a1*d1.x + a2*d2.x + a3*d3.x + a4*d4v.x + a5*d5.x + a6*d6.x + a7*d7.x;
        acc.y += a0*d0.y + a1*d1.y + a2*d2.y + a3*d3.y + a4*d4v.y + a5*d5.y + a6*d6.y + a7*d7.y;
        acc.z += a0*d0.z + a1*d1.z + a2*d2.z + a3*d3.z + a4*d4v.z + a5*d5.z + a6*d6.z + a7*d7.z;
        acc.w += a0*d0.w + a1*d1.w + a2*d2.w + a3*d3.w + a4*d4v.w + a5*d5.w + a6*d6.w + a7*d7.w;
        asum  += a0 + a1 + a2 + a3 + a4 + a5 + a6 + a7;
        dp += 8 * JS;
    }

    // ---- text term: same j coverage, L2-resident (1 MB/b) ----
    const float4* tp = text4 + ((size_t)(b * LL + g) * D4 + l);
    const size_t  TS = (size_t)4 * D4;        // +4 in j

    #pragma unroll 1
    for (int it = 0; it < 8; ++it) {
        const int jb = (it << 5) + g;
        const float a0 = adjs[jb +  0];
        const float a1 = adjs[jb +  4];
        const float a2 = adjs[jb +  8];
        const float a3 = adjs[jb + 12];
        const float a4 = adjs[jb + 16];
        const float a5 = adjs[jb + 20];
        const float a6 = adjs[jb + 24];
        const float a7 = adjs[jb + 28];
        const float4 t0 = tp[0 * TS];
        const float4 t1 = tp[1 * TS];
        const float4 t2 = tp[2 * TS];
        const float4 t3 = tp[3 * TS];
        const float4 t4 = tp[4 * TS];
        const float4 t5 = tp[5 * TS];
        const float4 t6 = tp[6 * TS];
        const float4 t7 = tp[7 * TS];
        acc.x += a0*t0.x + a1*t1.x + a2*t2.x + a3*t3.x + a4*t4.x + a5*t5.x + a6*t6.x + a7*t7.x;
        acc.y += a0*t0.y + a1*t1.y + a2*t2.y + a3*t3.y + a4*t4.y + a5*t5.y + a6*t6.y + a7*t7.y;
        acc.z += a0*t0.z + a1*t1.z + a2*t2.z + a3*t3.z + a4*t4.z + a5*t5.z + a6*t6.z + a7*t7.z;
        acc.w += a0*t0.w + a1*t1.w + a2*t2.w + a3*t3.w + a4*t4.w + a5*t5.w + a6*t6.w + a7*t7.w;
        tp += 8 * TS;
    }

    red[g][l] = acc;
    if (l == 0) ared[g] = asum;
    __syncthreads();

    if (g == 0) {
        const float4 r0 = red[0][l], r1 = red[1][l], r2 = red[2][l], r3 = red[3][l];
        float4 s;
        s.x = r0.x + r1.x + r2.x + r3.x;
        s.y = r0.y + r1.y + r2.y + r3.y;
        s.z = r0.z + r1.z + r2.z + r3.z;
        s.w = r0.w + r1.w + r2.w + r3.w;
        sfin[l] = s;
    }
    __syncthreads();

    const float A = ared[0] + ared[1] + ared[2] + ared[3];

    // ---- epilogue: thread t = output column o; W L1/L2-resident ----
    const float4* W4 = (const float4*)W;
    float oacc = 0.f;
    #pragma unroll 8
    for (int d4 = 0; d4 < D4; ++d4) {
        const float4 s = sfin[d4];
        const float4 w = W4[t * D4 + d4];
        oacc += s.x * w.x + s.y * w.y + s.z * w.z + s.w * w.w;
    }
    out[bi * DD + t] = oacc + A * bias[t];
}

extern "C" void kernel_launch(void* const* d_in, const int* in_sizes, int n_in,
                              void* d_out, int out_size, void* d_ws, size_t ws_size,
                              hipStream_t stream) {
    const float* text = (const float*)d_in[0];
    const float* adj  = (const float*)d_in[1];
    const float* dep  = (const float*)d_in[2];
    const float* W    = (const float*)d_in[3];
    const float* bias = (const float*)d_in[4];
    float* out = (float*)d_out;

    tgc_fused_kernel<<<dim3(1024), dim3(256), 0, stream>>>(text, adj, dep, W, bias, out);
}